// Round 1
// baseline (436.486 us; speedup 1.0000x reference)
//
#include <hip/hip_runtime.h>
#include <math.h>

namespace {
constexpr int B_   = 8;
constexpr int DIM_ = 2048;
constexpr int H_   = 16;
constexpr int QLR_ = 1536;
constexpr int KVLR_= 512;
constexpr int DN_  = 128;
constexpr int DR_  = 64;
constexpr int DV_  = 128;
constexpr int TPRE_= 8191;
constexpr int CE_  = 576;    // KVLR + DR
constexpr int NCH_ = 32;     // chunks over T=8192
constexpr int CT_  = 256;    // t per chunk
constexpr float EPS_ = 1e-6f;
constexpr float SCALE_ = 0.07216878364870322f; // (DN+DR)^-0.5
constexpr int SSTR_ = 20;    // padded LDS stride for score tile [256][20]

// workspace layout (float offsets)
constexpr size_t WS_QLAT  = 0;
constexpr size_t WS_KVPE  = WS_QLAT  + (size_t)B_*QLR_;
constexpr size_t WS_KVNEW = WS_KVPE  + (size_t)B_*CE_;
constexpr size_t WS_PENEW = WS_KVNEW + (size_t)B_*KVLR_;
constexpr size_t WS_QNOPE = WS_PENEW + (size_t)B_*DR_;
constexpr size_t WS_QT    = WS_QNOPE + (size_t)B_*H_*DN_;   // [b][576][16]
constexpr size_t WS_MLOC  = WS_QT    + (size_t)B_*CE_*H_;
constexpr size_t WS_LLOC  = WS_MLOC  + (size_t)B_*H_*NCH_;
constexpr size_t WS_OUT2  = WS_LLOC  + (size_t)B_*H_*NCH_;
constexpr size_t WS_OPART = WS_OUT2  + (size_t)B_*DIM_;     // [b][h][chunk][512]
} // namespace

// ---------------- K1: q_latent = x@wq_a^T + b ; kvpe = x@wkv_a^T + b ----------------
__global__ __launch_bounds__(256) void mla_k1(const float* __restrict__ x,
                                              const float* __restrict__ wqa,
                                              const float* __restrict__ bqa,
                                              const float* __restrict__ wkva,
                                              const float* __restrict__ bkva,
                                              float* __restrict__ ws) {
  __shared__ float xs[B_ * DIM_]; // 64 KB
  const int tid = threadIdx.x;
  {
    const float4* xg = (const float4*)x;
    float4* xl = (float4*)xs;
    for (int i = tid; i < B_ * DIM_ / 4; i += 256) xl[i] = xg[i];
  }
  __syncthreads();
  const int w = tid >> 6, l = tid & 63;
  const int r0 = blockIdx.x * 8 + w * 2;
  const float* W; const float* bias; float* out; int rr; int ostride;
  if (r0 < QLR_) { W = wqa;  bias = bqa;  out = ws + WS_QLAT; rr = r0;        ostride = QLR_; }
  else           { W = wkva; bias = bkva; out = ws + WS_KVPE; rr = r0 - QLR_; ostride = CE_;  }
  float acc0[B_], acc1[B_];
#pragma unroll
  for (int b = 0; b < B_; ++b) { acc0[b] = 0.f; acc1[b] = 0.f; }
  const float4* w0p = (const float4*)(W + (size_t)rr * DIM_);
  const float4* w1p = (const float4*)(W + (size_t)(rr + 1) * DIM_);
  const float4* xl4 = (const float4*)xs;
#pragma unroll
  for (int j = 0; j < DIM_ / 256; ++j) { // 8
    const int c4 = l + 64 * j;
    const float4 w0 = w0p[c4];
    const float4 w1 = w1p[c4];
#pragma unroll
    for (int b = 0; b < B_; ++b) {
      const float4 xv = xl4[b * (DIM_ / 4) + c4];
      acc0[b] = fmaf(w0.x, xv.x, fmaf(w0.y, xv.y, fmaf(w0.z, xv.z, fmaf(w0.w, xv.w, acc0[b]))));
      acc1[b] = fmaf(w1.x, xv.x, fmaf(w1.y, xv.y, fmaf(w1.z, xv.z, fmaf(w1.w, xv.w, acc1[b]))));
    }
  }
#pragma unroll
  for (int b = 0; b < B_; ++b) {
#pragma unroll
    for (int s = 32; s; s >>= 1) {
      acc0[b] += __shfl_xor(acc0[b], s);
      acc1[b] += __shfl_xor(acc1[b], s);
    }
  }
  if (l == 0) {
    const float b0 = bias[rr], b1 = bias[rr + 1];
#pragma unroll
    for (int b = 0; b < B_; ++b) {
      out[b * ostride + rr]     = acc0[b] + b0;
      out[b * ostride + rr + 1] = acc1[b] + b1;
    }
  }
}

// ---------------- K2: kv_new = rms(kvpe[:512])*kv_norm_w ; pe_new = rope(kvpe[512:576]) ----------------
__global__ __launch_bounds__(256) void mla_k2(const float* __restrict__ kvnw,
                                              const float* __restrict__ fcos,
                                              const float* __restrict__ fsin,
                                              float* __restrict__ ws) {
  const int tid = threadIdx.x;
  const int b = tid >> 5, i = tid & 31;
  const float* kvpe = ws + WS_KVPE + b * CE_;
  float ss = 0.f;
#pragma unroll
  for (int j = 0; j < KVLR_ / 32; ++j) { const float v = kvpe[i + 32 * j]; ss = fmaf(v, v, ss); }
#pragma unroll
  for (int s = 16; s; s >>= 1) ss += __shfl_xor(ss, s, 32);
  const float scale = 1.0f / sqrtf(ss / (float)KVLR_ + EPS_);
  float* kvn = ws + WS_KVNEW + b * KVLR_;
#pragma unroll
  for (int j = 0; j < KVLR_ / 32; ++j) {
    const int c = i + 32 * j;
    kvn[c] = kvpe[c] * kvnw[c] * scale;
  }
  // rope new k_pe (32 pairs per batch)
  const float xr = kvpe[KVLR_ + 2 * i], xi = kvpe[KVLR_ + 2 * i + 1];
  const float c = fcos[i], s = fsin[i];
  float* pen = ws + WS_PENEW + b * DR_;
  pen[2 * i]     = xr * c - xi * s;
  pen[2 * i + 1] = xr * s + xi * c;
}

// ---------------- K3: q = rms(q_lat)*q_norm_w @ wq_b^T + b ; split nope / rope(pe) ----------------
__global__ __launch_bounds__(256) void mla_k3(const float* __restrict__ qnw,
                                              const float* __restrict__ wqb,
                                              const float* __restrict__ bqb,
                                              const float* __restrict__ fcos,
                                              const float* __restrict__ fsin,
                                              float* __restrict__ ws) {
  __shared__ float xs[B_ * QLR_]; // 48 KB normalized q_latent
  __shared__ float sq[B_];
  const int tid = threadIdx.x;
  const float* qlat = ws + WS_QLAT;
  {
    const int b = tid >> 5, i = tid & 31;
    const float* p = qlat + b * QLR_;
    float ss = 0.f;
#pragma unroll
    for (int j = 0; j < QLR_ / 32; ++j) { const float v = p[i + 32 * j]; ss = fmaf(v, v, ss); }
#pragma unroll
    for (int s = 16; s; s >>= 1) ss += __shfl_xor(ss, s, 32);
    if (i == 0) sq[b] = 1.0f / sqrtf(ss / (float)QLR_ + EPS_);
  }
  __syncthreads();
  for (int idx = tid; idx < B_ * QLR_ / 4; idx += 256) {
    const int b = idx / (QLR_ / 4);
    const int c4 = idx - b * (QLR_ / 4);
    const float4 v = ((const float4*)qlat)[idx];
    const float4 g = ((const float4*)qnw)[c4];
    const float s = sq[b];
    float4 o; o.x = v.x * g.x * s; o.y = v.y * g.y * s; o.z = v.z * g.z * s; o.w = v.w * g.w * s;
    ((float4*)xs)[idx] = o;
  }
  __syncthreads();
  const int w = tid >> 6, l = tid & 63;
  const int r0 = blockIdx.x * 8 + w * 2;
  float acc0[B_], acc1[B_];
#pragma unroll
  for (int b = 0; b < B_; ++b) { acc0[b] = 0.f; acc1[b] = 0.f; }
  const float4* w0p = (const float4*)(wqb + (size_t)r0 * QLR_);
  const float4* w1p = (const float4*)(wqb + (size_t)(r0 + 1) * QLR_);
  const float4* xl4 = (const float4*)xs;
#pragma unroll
  for (int j = 0; j < QLR_ / 256; ++j) { // 6
    const int c4 = l + 64 * j;
    const float4 w0 = w0p[c4];
    const float4 w1 = w1p[c4];
#pragma unroll
    for (int b = 0; b < B_; ++b) {
      const float4 xv = xl4[b * (QLR_ / 4) + c4];
      acc0[b] = fmaf(w0.x, xv.x, fmaf(w0.y, xv.y, fmaf(w0.z, xv.z, fmaf(w0.w, xv.w, acc0[b]))));
      acc1[b] = fmaf(w1.x, xv.x, fmaf(w1.y, xv.y, fmaf(w1.z, xv.z, fmaf(w1.w, xv.w, acc1[b]))));
    }
  }
#pragma unroll
  for (int b = 0; b < B_; ++b) {
#pragma unroll
    for (int s = 32; s; s >>= 1) {
      acc0[b] += __shfl_xor(acc0[b], s);
      acc1[b] += __shfl_xor(acc1[b], s);
    }
  }
  if (l == 0) {
    const int h = r0 / (DN_ + DR_);
    const int j0 = r0 - h * (DN_ + DR_);
    const float b0 = bqb[r0], b1 = bqb[r0 + 1];
    if (j0 < DN_) {
      float* qn = ws + WS_QNOPE;
#pragma unroll
      for (int b = 0; b < B_; ++b) {
        qn[(b * H_ + h) * DN_ + j0]     = acc0[b] + b0;
        qn[(b * H_ + h) * DN_ + j0 + 1] = acc1[b] + b1;
      }
    } else {
      const int i = (j0 - DN_) >> 1;
      const float c = fcos[i], s = fsin[i];
      float* qT = ws + WS_QT;
#pragma unroll
      for (int b = 0; b < B_; ++b) {
        const float xr = acc0[b] + b0, xi = acc1[b] + b1;
        qT[((size_t)b * CE_ + KVLR_ + 2 * i) * H_ + h]     = xr * c - xi * s;
        qT[((size_t)b * CE_ + KVLR_ + 2 * i + 1) * H_ + h] = xr * s + xi * c;
      }
    }
  }
}

// ---------------- K4: q_abs[b][h][c] = sum_d q_nope[b][h][d] * wkv_b[h][d][c], into qT[b][c][h] ----------------
__global__ __launch_bounds__(256) void mla_k4(const float* __restrict__ wkvb,
                                              float* __restrict__ ws) {
  __shared__ float red[128 * B_];
  const int h = blockIdx.y;
  const int cs = blockIdx.x;
  const int tid = threadIdx.x;
  const int c = tid & 127, dh = tid >> 7;
  const int cg = cs * 128 + c;
  const float* qn = ws + WS_QNOPE;
  float acc[B_];
#pragma unroll
  for (int b = 0; b < B_; ++b) acc[b] = 0.f;
  const float* wp = wkvb + (size_t)h * 256 * KVLR_ + cg;
  for (int d = dh * 64; d < dh * 64 + 64; ++d) {
    const float wv = wp[(size_t)d * KVLR_];
#pragma unroll
    for (int b = 0; b < B_; ++b) acc[b] = fmaf(qn[(b * H_ + h) * DN_ + d], wv, acc[b]);
  }
  if (dh == 1) {
#pragma unroll
    for (int b = 0; b < B_; ++b) red[c * B_ + b] = acc[b];
  }
  __syncthreads();
  if (dh == 0) {
    float* qT = ws + WS_QT;
#pragma unroll
    for (int b = 0; b < B_; ++b) {
      qT[((size_t)b * CE_ + cg) * H_ + h] = acc[b] + red[c * B_ + b];
    }
  }
}

// ---------------- K5: flash-decode partials per (b, chunk) ----------------
__global__ __launch_bounds__(256) void mla_k5(const float* __restrict__ kvpre,
                                              const float* __restrict__ pepre,
                                              float* __restrict__ ws) {
  __shared__ float sl[CT_ * SSTR_]; // 20 KB scores -> p
  const int b = blockIdx.y;
  const int chunk = blockIdx.x;
  const int t0 = chunk * CT_;
  const int tid = threadIdx.x;
  const int w = tid >> 6, l = tid & 63;
  const float* kvnew = ws + WS_KVNEW;
  const float* penew = ws + WS_PENEW;

  // ---- phase A: scores, lane <-> t, q via wave-uniform scalar loads ----
  {
    const int t = t0 + (w << 6) + l;
    const float* kvrow; const float* perow;
    if (t < TPRE_) {
      kvrow = kvpre + ((size_t)b * TPRE_ + t) * KVLR_;
      perow = pepre + ((size_t)b * TPRE_ + t) * DR_;
    } else {
      kvrow = kvnew + b * KVLR_;
      perow = penew + b * DR_;
    }
    const float* qTb = ws + WS_QT + (size_t)b * CE_ * H_;
    float acc[H_];
#pragma unroll
    for (int h = 0; h < H_; ++h) acc[h] = 0.f;
    for (int c4 = 0; c4 < KVLR_; c4 += 4) {
      const float4 k = *(const float4*)(kvrow + c4);
      const float* qc = qTb + (size_t)c4 * H_;
#pragma unroll
      for (int h = 0; h < H_; ++h) {
        acc[h] = fmaf(qc[h], k.x, acc[h]);
        acc[h] = fmaf(qc[H_ + h], k.y, acc[h]);
        acc[h] = fmaf(qc[2 * H_ + h], k.z, acc[h]);
        acc[h] = fmaf(qc[3 * H_ + h], k.w, acc[h]);
      }
    }
    for (int c4 = 0; c4 < DR_; c4 += 4) {
      const float4 k = *(const float4*)(perow + c4);
      const float* qc = qTb + (size_t)(KVLR_ + c4) * H_;
#pragma unroll
      for (int h = 0; h < H_; ++h) {
        acc[h] = fmaf(qc[h], k.x, acc[h]);
        acc[h] = fmaf(qc[H_ + h], k.y, acc[h]);
        acc[h] = fmaf(qc[2 * H_ + h], k.z, acc[h]);
        acc[h] = fmaf(qc[3 * H_ + h], k.w, acc[h]);
      }
    }
    const int tl = (w << 6) + l;
#pragma unroll
    for (int g = 0; g < 4; ++g) {
      float4 v;
      v.x = acc[4 * g] * SCALE_; v.y = acc[4 * g + 1] * SCALE_;
      v.z = acc[4 * g + 2] * SCALE_; v.w = acc[4 * g + 3] * SCALE_;
      *(float4*)(sl + tl * SSTR_ + 4 * g) = v;
    }
  }
  __syncthreads();

  // ---- phase B: chunk-local softmax per head ----
  {
    const int h2 = tid >> 4, grp = tid & 15;
    float m = -3.4e38f;
#pragma unroll
    for (int j = 0; j < 16; ++j) m = fmaxf(m, sl[(grp + 16 * j) * SSTR_ + h2]);
#pragma unroll
    for (int s = 8; s; s >>= 1) m = fmaxf(m, __shfl_xor(m, s, 16));
    float lsum = 0.f;
#pragma unroll
    for (int j = 0; j < 16; ++j) {
      const int idx = (grp + 16 * j) * SSTR_ + h2;
      const float p = __expf(sl[idx] - m);
      sl[idx] = p;
      lsum += p;
    }
#pragma unroll
    for (int s = 8; s; s >>= 1) lsum += __shfl_xor(lsum, s, 16);
    if (grp == 0) {
      ws[WS_MLOC + (b * H_ + h2) * NCH_ + chunk] = m;
      ws[WS_LLOC + (b * H_ + h2) * NCH_ + chunk] = lsum;
    }
  }
  __syncthreads();

  // ---- phase C: O_partial = sum_t p * kv  (wave <-> 4 heads, lanes <-> c, coalesced) ----
  {
    float o[4][8];
#pragma unroll
    for (int a = 0; a < 4; ++a)
#pragma unroll
      for (int j = 0; j < 8; ++j) o[a][j] = 0.f;
    const int hb = w * 4;
    const float* kvb = kvpre + (size_t)b * TPRE_ * KVLR_;
    for (int t = 0; t < CT_; ++t) {
      const int tg = t0 + t;
      const float* kr = (tg < TPRE_) ? (kvb + (size_t)tg * KVLR_) : (kvnew + b * KVLR_);
      const float4 p = *(const float4*)(sl + t * SSTR_ + hb);
#pragma unroll
      for (int j = 0; j < 4; ++j) {
        const float2 kv = *(const float2*)(kr + j * 128 + 2 * l);
        o[0][2 * j]     = fmaf(p.x, kv.x, o[0][2 * j]);
        o[0][2 * j + 1] = fmaf(p.x, kv.y, o[0][2 * j + 1]);
        o[1][2 * j]     = fmaf(p.y, kv.x, o[1][2 * j]);
        o[1][2 * j + 1] = fmaf(p.y, kv.y, o[1][2 * j + 1]);
        o[2][2 * j]     = fmaf(p.z, kv.x, o[2][2 * j]);
        o[2][2 * j + 1] = fmaf(p.z, kv.y, o[2][2 * j + 1]);
        o[3][2 * j]     = fmaf(p.w, kv.x, o[3][2 * j]);
        o[3][2 * j + 1] = fmaf(p.w, kv.y, o[3][2 * j + 1]);
      }
    }
    float* Op = ws + WS_OPART;
#pragma unroll
    for (int a = 0; a < 4; ++a) {
#pragma unroll
      for (int j = 0; j < 4; ++j) {
        float2 v; v.x = o[a][2 * j]; v.y = o[a][2 * j + 1];
        *(float2*)(Op + (((size_t)(b * H_ + hb + a) * NCH_ + chunk) * KVLR_) + j * 128 + 2 * l) = v;
      }
    }
  }
}

// ---------------- K6: combine partials + project through wkv_b[:,128:,:] ----------------
__global__ __launch_bounds__(256) void mla_k6(const float* __restrict__ wkvb,
                                              float* __restrict__ ws) {
  const int h = blockIdx.x, b = blockIdx.y;
  __shared__ float wgt[NCH_];
  __shared__ float ao[KVLR_];
  __shared__ float Linv;
  const int tid = threadIdx.x;
  if (tid < NCH_) {
    const float m = ws[WS_MLOC + (b * H_ + h) * NCH_ + tid];
    float M = m;
#pragma unroll
    for (int s = 16; s; s >>= 1) M = fmaxf(M, __shfl_xor(M, s, 32));
    const float wv = __expf(m - M);
    wgt[tid] = wv;
    float lv = ws[WS_LLOC + (b * H_ + h) * NCH_ + tid] * wv;
#pragma unroll
    for (int s = 16; s; s >>= 1) lv += __shfl_xor(lv, s, 32);
    if (tid == 0) Linv = 1.0f / lv;
  }
  __syncthreads();
  const float* Ob = ws + WS_OPART + (size_t)(b * H_ + h) * NCH_ * KVLR_;
  float s0 = 0.f, s1 = 0.f;
#pragma unroll 4
  for (int i = 0; i < NCH_; ++i) {
    const float wv = wgt[i];
    s0 = fmaf(wv, Ob[(size_t)i * KVLR_ + tid], s0);
    s1 = fmaf(wv, Ob[(size_t)i * KVLR_ + tid + 256], s1);
  }
  const float li = Linv;
  ao[tid] = s0 * li;
  ao[tid + 256] = s1 * li;
  __syncthreads();
  const int v = tid >> 1, half = tid & 1;
  const float* w2 = wkvb + ((size_t)h * 256 + DN_ + v) * KVLR_ + half * 256;
  const float* a = ao + half * 256;
  float s = 0.f;
#pragma unroll
  for (int c = 0; c < 256; c += 4) {
    const float4 wv = *(const float4*)(w2 + c);
    s = fmaf(wv.x, a[c], s);
    s = fmaf(wv.y, a[c + 1], s);
    s = fmaf(wv.z, a[c + 2], s);
    s = fmaf(wv.w, a[c + 3], s);
  }
  s += __shfl_xor(s, 1);
  if (half == 0) ws[WS_OUT2 + b * DIM_ + h * DV_ + v] = s;
}

// ---------------- K7: y = out2 @ wo^T + wo_b ----------------
__global__ __launch_bounds__(256) void mla_k7(const float* __restrict__ wo,
                                              const float* __restrict__ wob,
                                              const float* __restrict__ ws,
                                              float* __restrict__ out) {
  __shared__ float xs[B_ * DIM_]; // 64 KB
  const int tid = threadIdx.x;
  {
    const float4* xg = (const float4*)(ws + WS_OUT2);
    float4* xl = (float4*)xs;
    for (int i = tid; i < B_ * DIM_ / 4; i += 256) xl[i] = xg[i];
  }
  __syncthreads();
  const int w = tid >> 6, l = tid & 63;
  const int r0 = blockIdx.x * 8 + w * 2;
  float acc0[B_], acc1[B_];
#pragma unroll
  for (int b = 0; b < B_; ++b) { acc0[b] = 0.f; acc1[b] = 0.f; }
  const float4* w0p = (const float4*)(wo + (size_t)r0 * DIM_);
  const float4* w1p = (const float4*)(wo + (size_t)(r0 + 1) * DIM_);
  const float4* xl4 = (const float4*)xs;
#pragma unroll
  for (int j = 0; j < DIM_ / 256; ++j) { // 8
    const int c4 = l + 64 * j;
    const float4 w0 = w0p[c4];
    const float4 w1 = w1p[c4];
#pragma unroll
    for (int b = 0; b < B_; ++b) {
      const float4 xv = xl4[b * (DIM_ / 4) + c4];
      acc0[b] = fmaf(w0.x, xv.x, fmaf(w0.y, xv.y, fmaf(w0.z, xv.z, fmaf(w0.w, xv.w, acc0[b]))));
      acc1[b] = fmaf(w1.x, xv.x, fmaf(w1.y, xv.y, fmaf(w1.z, xv.z, fmaf(w1.w, xv.w, acc1[b]))));
    }
  }
#pragma unroll
  for (int b = 0; b < B_; ++b) {
#pragma unroll
    for (int s = 32; s; s >>= 1) {
      acc0[b] += __shfl_xor(acc0[b], s);
      acc1[b] += __shfl_xor(acc1[b], s);
    }
  }
  if (l == 0) {
    const float b0 = wob[r0], b1 = wob[r0 + 1];
#pragma unroll
    for (int b = 0; b < B_; ++b) {
      out[b * DIM_ + r0]     = acc0[b] + b0;
      out[b * DIM_ + r0 + 1] = acc1[b] + b1;
    }
  }
}

extern "C" void kernel_launch(void* const* d_in, const int* in_sizes, int n_in,
                              void* d_out, int out_size, void* d_ws, size_t ws_size,
                              hipStream_t stream) {
  (void)in_sizes; (void)n_in; (void)out_size; (void)ws_size;
  const float* x     = (const float*)d_in[0];
  // d_in[1] = start_pos (fixed 8191 by problem shape)
  const float* fcos  = (const float*)d_in[2];
  const float* fsin  = (const float*)d_in[3];
  const float* kvpre = (const float*)d_in[4];
  const float* pepre = (const float*)d_in[5];
  const float* wqa   = (const float*)d_in[6];
  const float* bqa   = (const float*)d_in[7];
  const float* qnw   = (const float*)d_in[8];
  const float* wqb   = (const float*)d_in[9];
  const float* bqb   = (const float*)d_in[10];
  const float* wkva  = (const float*)d_in[11];
  const float* bkva  = (const float*)d_in[12];
  const float* kvnw  = (const float*)d_in[13];
  const float* wkvb  = (const float*)d_in[14];
  const float* wo    = (const float*)d_in[15];
  const float* wob   = (const float*)d_in[16];
  float* ws  = (float*)d_ws;
  float* out = (float*)d_out;

  mla_k1<<<dim3((QLR_ + CE_) / 8), dim3(256), 0, stream>>>(x, wqa, bqa, wkva, bkva, ws);
  mla_k2<<<dim3(1), dim3(256), 0, stream>>>(kvnw, fcos, fsin, ws);
  mla_k3<<<dim3(H_ * (DN_ + DR_) / 8), dim3(256), 0, stream>>>(qnw, wqb, bqb, fcos, fsin, ws);
  mla_k4<<<dim3(4, 16), dim3(256), 0, stream>>>(wkvb, ws);
  mla_k5<<<dim3(NCH_, B_), dim3(256), 0, stream>>>(kvpre, pepre, ws);
  mla_k6<<<dim3(H_, B_), dim3(256), 0, stream>>>(wkvb, ws);
  mla_k7<<<dim3(DIM_ / 8), dim3(256), 0, stream>>>(wo, wob, ws, out);
}